// Round 3
// baseline (10804.873 us; speedup 1.0000x reference)
//
#include <hip/hip_runtime.h>
#include <math.h>

#define B_  32
#define D_  1000
#define Q_  50
#define E_  384
#define H_  384
#define G3_ 1152
#define C_  10
#define P_  192   // H_/2 pairs

typedef _Float16 f16;
typedef f16 f16x2 __attribute__((ext_vector_type(2)));

// ---------------- pack Whh (both dirs) -> fp16 pair-planes WTP[dir][gate][p][j] ----------------
__global__ __launch_bounds__(256) void k_packw(const float* __restrict__ Wf,
                                               const float* __restrict__ Wb,
                                               f16x2* __restrict__ WTP) {
  int idx = blockIdx.x * 256 + threadIdx.x;        // over 3*192*384 = 221184
  if (idx >= 3 * P_ * H_) return;
  int g = idx / (P_ * H_);
  int rem = idx % (P_ * H_);
  int p = rem / H_, j = rem % H_;
  const float* W = blockIdx.y ? Wb : Wf;           // row-major [1152][384]
  float a = W[(size_t)(g * H_ + j) * H_ + 2 * p];
  float b = W[(size_t)(g * H_ + j) * H_ + 2 * p + 1];
  WTP[(size_t)blockIdx.y * 3 * P_ * H_ + idx] = (f16x2){(f16)a, (f16)b};
}

// ---------------- fused gather+projection for a time-chunk ----------------
// out[dir][b][s_local][g] = emb[tok[b][pos]] . Wih_dir[g] + bih_dir[g]
// pos = dir==0 ? (c*CT+s_local) : (len-1-(c*CT+s_local)), clamped; rows with
// s >= len produce values the GRU never reads.
__global__ __launch_bounds__(256) void k_projx(
    const int* __restrict__ toks, const int* __restrict__ lens, int T, int CT, int c,
    const float* __restrict__ emb,
    const float* __restrict__ Wih_f, const float* __restrict__ bih_f,
    const float* __restrict__ Wih_b, const float* __restrict__ bih_b,
    float* __restrict__ outbuf) {
  int dir = blockIdx.z;
  const float* W    = dir ? Wih_b : Wih_f;
  const float* bias = dir ? bih_b : bih_f;
  float* Cout = outbuf + (size_t)dir * B_ * CT * G3_;
  int nrows = B_ * CT;
  int r0 = blockIdx.x * 64, g0 = blockIdx.y * 64;
  int tid = threadIdx.x;

  // resolve each loaded row's embedding pointer once
  const float* aRow[4];
  #pragma unroll
  for (int i = 0; i < 4; ++i) {
    int rr = (tid + 256 * i) >> 4;
    int row = r0 + rr; if (row >= nrows) row = nrows - 1;
    int b = row / CT, sl = row % CT;
    int s = c * CT + sl;
    int len = lens[b];
    int pos = dir ? (len - 1 - s) : s;
    if (pos < 0) pos = 0;
    if (pos >= T) pos = T - 1;
    aRow[i] = emb + (size_t)toks[b * T + pos] * E_;
  }

  __shared__ float As[64][17];
  __shared__ float Ws_[64][17];
  float acc[4][4] = {};
  for (int ec = 0; ec < E_; ec += 16) {
    #pragma unroll
    for (int i = 0; i < 4; ++i) {
      int lin = tid + 256 * i;
      int rr = lin >> 4, cc = lin & 15;
      As[rr][cc]  = aRow[i][ec + cc];
      Ws_[rr][cc] = W[(size_t)(g0 + rr) * E_ + ec + cc];
    }
    __syncthreads();
    int ty = tid >> 4, tx = tid & 15;
    #pragma unroll
    for (int kk = 0; kk < 16; ++kk) {
      float a[4], w[4];
      #pragma unroll
      for (int i = 0; i < 4; ++i) a[i] = As[ty + 16 * i][kk];
      #pragma unroll
      for (int j = 0; j < 4; ++j) w[j] = Ws_[tx + 16 * j][kk];
      #pragma unroll
      for (int i = 0; i < 4; ++i)
        #pragma unroll
        for (int j = 0; j < 4; ++j) acc[i][j] = fmaf(a[i], w[j], acc[i][j]);
    }
    __syncthreads();
  }
  int ty = tid >> 4, tx = tid & 15;
  #pragma unroll
  for (int i = 0; i < 4; ++i) {
    int row = r0 + ty + 16 * i;
    if (row < nrows) {
      #pragma unroll
      for (int j = 0; j < 4; ++j) {
        int g = g0 + tx + 16 * j;
        Cout[(size_t)row * G3_ + g] = acc[i][j] + bias[g];
      }
    }
  }
}

// ---------------- GRU chunk: one WG per (seq, dir); h carried in global ----------------
__global__ __launch_bounds__(384) void k_gruc(
    const float* __restrict__ xwC, int T, int CT, int c, int init,
    const f16x2* __restrict__ WTP,
    const float* __restrict__ bhhf, const float* __restrict__ bhhb,
    const int* __restrict__ lens,
    float* __restrict__ outbase, float* __restrict__ hcar) {
  int wg = blockIdx.x;            // 2*B_ WGs
  int b = wg % B_, dir = wg / B_;
  int len = lens[b];
  int s0 = c * CT;
  int cnt = len - s0;
  if (cnt > CT) cnt = CT;
  if (cnt < 0) cnt = 0;
  const float* xw = xwC + (size_t)(dir * B_ + b) * CT * G3_;
  const f16x2* Wd = WTP + (size_t)dir * 3 * P_ * H_;
  const f16x2* wr = Wd;
  const f16x2* wz = Wd + (size_t)P_ * H_;
  const f16x2* wn = Wd + (size_t)2 * P_ * H_;
  const float* bhh = dir ? bhhb : bhhf;
  float* out = outbase + (size_t)b * T * 2 * H_ + dir * H_;
  float* hc = hcar + (size_t)(dir * B_ + b) * H_;

  int j = threadIdx.x;
  __shared__ f16x2 hs2[P_];
  f16* hs = (f16*)hs2;
  float hreg = init ? 0.f : hc[j];
  hs[j] = (f16)hreg;
  float br = bhh[j], bz = bhh[H_ + j], bn = bhh[2 * H_ + j];
  __syncthreads();

  for (int sl = 0; sl < cnt; ++sl) {
    int s = s0 + sl;
    int pos = dir ? (len - 1 - s) : s;
    const float* xp = xw + (size_t)sl * G3_;
    float hr = br, hz = bz, hn = bn;
    #pragma unroll 16
    for (int p = 0; p < P_; ++p) {
      f16x2 hp = hs2[p];               // uniform address -> LDS broadcast
      f16x2 a = wr[p * H_ + j];
      f16x2 cc = wz[p * H_ + j];
      f16x2 d = wn[p * H_ + j];
#if __has_builtin(__builtin_amdgcn_fdot2)
      hr = __builtin_amdgcn_fdot2(a, hp, hr, false);
      hz = __builtin_amdgcn_fdot2(cc, hp, hz, false);
      hn = __builtin_amdgcn_fdot2(d, hp, hn, false);
#else
      hr = fmaf((float)a.x, (float)hp.x, hr); hr = fmaf((float)a.y, (float)hp.y, hr);
      hz = fmaf((float)cc.x, (float)hp.x, hz); hz = fmaf((float)cc.y, (float)hp.y, hz);
      hn = fmaf((float)d.x, (float)hp.x, hn); hn = fmaf((float)d.y, (float)hp.y, hn);
#endif
    }
    float r = 1.f / (1.f + expf(-(xp[j] + hr)));
    float z = 1.f / (1.f + expf(-(xp[H_ + j] + hz)));
    float n = tanhf(xp[2 * H_ + j] + r * hn);
    float hnew = (1.f - z) * n + z * hreg;
    __syncthreads();                   // all dot-reads of hs done
    hs[j] = (f16)hnew;
    hreg = hnew;
    out[(size_t)pos * 2 * H_ + j] = hnew;
    __syncthreads();                   // hs visible for next step
  }
  hc[j] = hreg;
}

// ---------------- M[b,d,q] = dot(dos[b,d,:], qos[b,q,:]) ----------------
__global__ __launch_bounds__(256) void k_scores(const float* __restrict__ dos,
                                                const float* __restrict__ qos,
                                                const int* __restrict__ dlen,
                                                const int* __restrict__ qlen,
                                                float* __restrict__ M) {
  int b = blockIdx.x, d0 = blockIdx.y * 64;
  if (d0 >= dlen[b]) return;
  __shared__ float Ds[64][65];
  __shared__ float Qs[50][65];
  int tid = threadIdx.x;
  int lane = tid & 63, qg = tid >> 6;
  float acc[13];
  #pragma unroll
  for (int i = 0; i < 13; ++i) acc[i] = 0.f;
  for (int kc = 0; kc < 2 * H_; kc += 64) {
    #pragma unroll
    for (int i = 0; i < 16; ++i) {
      int lin = tid + 256 * i;
      int rr = lin >> 6, cc = lin & 63;
      int dd = d0 + rr; if (dd >= D_) dd = D_ - 1;   // clamp: avoid OOB, value unused
      Ds[rr][cc] = dos[((size_t)b * D_ + dd) * (2 * H_) + kc + cc];
    }
    #pragma unroll
    for (int i = 0; i < 13; ++i) {
      int lin = tid + 256 * i;
      if (lin < 3200) {
        int rr = lin >> 6, cc = lin & 63;
        Qs[rr][cc] = qos[((size_t)b * Q_ + rr) * (2 * H_) + kc + cc];
      }
    }
    __syncthreads();
    #pragma unroll 8
    for (int kk = 0; kk < 64; ++kk) {
      float dv = Ds[lane][kk];
      #pragma unroll
      for (int i = 0; i < 13; ++i) {
        int q = qg + 4 * i;
        if (q < 50) acc[i] = fmaf(dv, Qs[q][kk], acc[i]);
      }
    }
    __syncthreads();
  }
  if (d0 + lane < D_) {
    #pragma unroll
    for (int i = 0; i < 13; ++i) {
      int q = qg + 4 * i;
      if (q < 50) M[((size_t)b * D_ + d0 + lane) * 50 + q] = acc[i];
    }
  }
}

// ---------------- row stats (beta softmax over q) ----------------
__global__ __launch_bounds__(256) void k_rowstats(const float* __restrict__ M,
                                                  const int* __restrict__ dlen,
                                                  const int* __restrict__ qlen,
                                                  float* __restrict__ rowmax,
                                                  float* __restrict__ rowsum) {
  int b = blockIdx.x;
  int d = blockIdx.y * 256 + threadIdx.x;
  if (d >= dlen[b]) return;
  int ql = qlen[b];
  const float* row = M + ((size_t)b * D_ + d) * 50;
  float m = 0.f;                // ref max over full q-axis; masked entries are 0
  for (int q = 0; q < ql; ++q) m = fmaxf(m, row[q]);
  float s = 0.f;
  for (int q = 0; q < ql; ++q) s += expf(row[q] - m);
  rowmax[b * D_ + d] = m;
  rowsum[b * D_ + d] = s;
}

// ---------------- col stats (alpha softmax over d) + avg_beta ----------------
__global__ __launch_bounds__(256) void k_colstats(const float* __restrict__ M,
                                                  const int* __restrict__ dlen,
                                                  const int* __restrict__ qlen,
                                                  const float* __restrict__ rowmax,
                                                  const float* __restrict__ rowsum,
                                                  float* __restrict__ colmax,
                                                  float* __restrict__ colsum,
                                                  float* __restrict__ avg_beta) {
  int b = blockIdx.x, q = blockIdx.y;
  if (q >= qlen[b]) return;
  int dl = dlen[b];
  int tid = threadIdx.x;
  __shared__ float red[4];
  __shared__ float r1[4], r2[4];
  float m = 0.f;
  for (int d = tid; d < dl; d += 256) m = fmaxf(m, M[((size_t)b * D_ + d) * 50 + q]);
  for (int o = 32; o > 0; o >>= 1) m = fmaxf(m, __shfl_down(m, o, 64));
  if ((tid & 63) == 0) red[tid >> 6] = m;
  __syncthreads();
  m = fmaxf(fmaxf(red[0], red[1]), fmaxf(red[2], red[3]));
  float s1 = 0.f, s2 = 0.f;
  for (int d = tid; d < dl; d += 256) {
    float v = M[((size_t)b * D_ + d) * 50 + q];
    s1 += expf(v - m);
    s2 += expf(v - rowmax[b * D_ + d]) / (rowsum[b * D_ + d] + 1e-12f);
  }
  for (int o = 32; o > 0; o >>= 1) {
    s1 += __shfl_down(s1, o, 64);
    s2 += __shfl_down(s2, o, 64);
  }
  if ((tid & 63) == 0) { r1[tid >> 6] = s1; r2[tid >> 6] = s2; }
  __syncthreads();
  if (tid == 0) {
    colmax[b * 50 + q] = m;
    colsum[b * 50 + q] = r1[0] + r1[1] + r1[2] + r1[3];
    avg_beta[b * 50 + q] = (r2[0] + r2[1] + r2[2] + r2[3]) / (float)dl;
  }
}

// ---------------- s[b,d] = sum_q alpha * avg_beta ----------------
__global__ __launch_bounds__(256) void k_svec(const float* __restrict__ M,
                                              const int* __restrict__ dlen,
                                              const int* __restrict__ qlen,
                                              const float* __restrict__ colmax,
                                              const float* __restrict__ colsum,
                                              const float* __restrict__ avg_beta,
                                              float* __restrict__ svec) {
  int b = blockIdx.x;
  int d = blockIdx.y * 256 + threadIdx.x;
  if (d >= dlen[b]) return;
  int ql = qlen[b];
  const float* row = M + ((size_t)b * D_ + d) * 50;
  float s = 0.f;
  for (int q = 0; q < ql; ++q)
    s += expf(row[q] - colmax[b * 50 + q]) / (colsum[b * 50 + q] + 1e-12f) * avg_beta[b * 50 + q];
  svec[b * D_ + d] = s;
}

// ---------------- candidate pointer-sum ----------------
__global__ __launch_bounds__(256) void k_pointer(const int* __restrict__ docs,
                                                 const int* __restrict__ cand,
                                                 const int* __restrict__ dlen,
                                                 const float* __restrict__ svec,
                                                 float* __restrict__ out) {
  int b = blockIdx.x, tid = threadIdx.x;
  __shared__ int cs[C_];
  __shared__ float accs[C_];
  if (tid < C_) { cs[tid] = cand[b * C_ + tid]; accs[tid] = 0.f; }
  __syncthreads();
  float loc[C_];
  #pragma unroll
  for (int c = 0; c < C_; ++c) loc[c] = 0.f;
  int dl = dlen[b];
  for (int d = tid; d < dl; d += 256) {
    int t = docs[b * D_ + d];
    float sv = svec[b * D_ + d];
    #pragma unroll
    for (int c = 0; c < C_; ++c)
      if (t == cs[c]) loc[c] += sv;
  }
  #pragma unroll
  for (int c = 0; c < C_; ++c)
    if (loc[c] != 0.f) atomicAdd(&accs[c], loc[c]);
  __syncthreads();
  if (tid < C_) out[b * C_ + tid] = accs[tid];
}

extern "C" void kernel_launch(void* const* d_in, const int* in_sizes, int n_in,
                              void* d_out, int out_size, void* d_ws, size_t ws_size,
                              hipStream_t stream) {
  const int* docs_input   = (const int*)d_in[0];
  const int* docs_len     = (const int*)d_in[1];
  const int* querys_input = (const int*)d_in[2];
  const int* querys_len   = (const int*)d_in[3];
  const int* candidates   = (const int*)d_in[4];
  const float* emb   = (const float*)d_in[5];
  const float* Wih_f = (const float*)d_in[6];
  const float* Whh_f = (const float*)d_in[7];
  const float* bih_f = (const float*)d_in[8];
  const float* bhh_f = (const float*)d_in[9];
  const float* Wih_b = (const float*)d_in[10];
  const float* Whh_b = (const float*)d_in[11];
  const float* bih_b = (const float*)d_in[12];
  const float* bhh_b = (const float*)d_in[13];
  float* out = (float*)d_out;

  float* ws = (float*)d_ws;
  size_t off = 0;
  auto alloc = [&](size_t n) { float* p = ws + off; off += n; return p; };

  f16x2* WTP   = (f16x2*)alloc((size_t)2 * 3 * P_ * H_);  // 4B per f16x2
  float* xwQ   = alloc((size_t)2 * B_ * Q_ * G3_);
  float* qcar  = alloc((size_t)2 * B_ * H_);
  float* dcar  = alloc((size_t)2 * B_ * H_);
  float* dos   = alloc((size_t)B_ * D_ * 2 * H_);
  float* qos   = alloc((size_t)B_ * Q_ * 2 * H_);
  float* Mm    = alloc((size_t)B_ * D_ * 50);
  float* rowmax = alloc((size_t)B_ * D_);
  float* rowsum = alloc((size_t)B_ * D_);
  float* colmax = alloc((size_t)B_ * 50);
  float* colsum = alloc((size_t)B_ * 50);
  float* avgb   = alloc((size_t)B_ * 50);
  float* svec   = alloc((size_t)B_ * D_);

  // choose the largest doc-chunk CT whose xw buffer fits the remaining workspace
  const int cts[8] = {1000, 500, 250, 125, 50, 25, 10, 5};
  int CT = 5;
  for (int i = 0; i < 8; ++i) {
    size_t need = (off + (size_t)2 * B_ * cts[i] * G3_) * sizeof(float);
    if (need <= ws_size) { CT = cts[i]; break; }
  }
  float* xwC = alloc((size_t)2 * B_ * CT * G3_);
  int NC = (D_ + CT - 1) / CT;

  // weight packing
  k_packw<<<dim3((3 * P_ * H_ + 255) / 256, 2), 256, 0, stream>>>(Whh_f, Whh_b, WTP);

  // queries: single chunk (CT = Q_)
  k_projx<<<dim3((B_ * Q_ + 63) / 64, G3_ / 64, 2), 256, 0, stream>>>(
      querys_input, querys_len, Q_, Q_, 0, emb, Wih_f, bih_f, Wih_b, bih_b, xwQ);
  k_gruc<<<2 * B_, 384, 0, stream>>>(xwQ, Q_, Q_, 0, 1, WTP, bhh_f, bhh_b,
                                     querys_len, qos, qcar);

  // docs: chunked timeline
  for (int c = 0; c < NC; ++c) {
    k_projx<<<dim3((B_ * CT + 63) / 64, G3_ / 64, 2), 256, 0, stream>>>(
        docs_input, docs_len, D_, CT, c, emb, Wih_f, bih_f, Wih_b, bih_b, xwC);
    k_gruc<<<2 * B_, 384, 0, stream>>>(xwC, D_, CT, c, (c == 0) ? 1 : 0, WTP,
                                       bhh_f, bhh_b, docs_len, dos, dcar);
  }

  k_scores<<<dim3(B_, (D_ + 63) / 64), 256, 0, stream>>>(dos, qos, docs_len, querys_len, Mm);
  k_rowstats<<<dim3(B_, (D_ + 255) / 256), 256, 0, stream>>>(Mm, docs_len, querys_len, rowmax, rowsum);
  k_colstats<<<dim3(B_, 50), 256, 0, stream>>>(Mm, docs_len, querys_len, rowmax, rowsum,
                                               colmax, colsum, avgb);
  k_svec<<<dim3(B_, (D_ + 255) / 256), 256, 0, stream>>>(Mm, docs_len, querys_len,
                                                         colmax, colsum, avgb, svec);
  k_pointer<<<B_, 256, 0, stream>>>(docs_input, candidates, docs_len, svec, out);
}